// Round 1
// baseline (467.606 us; speedup 1.0000x reference)
//
#include <hip/hip_runtime.h>

// DelayBuffer: embeddings [B=4, S=4096, D=1024] f32.
// For each delay d in {1,2,4,8,16,32}: out_d[b,t,:] = emb[b, t-d, :] if t>=d else emb[b,t,:].
// Output = concat over delays on last dim -> [B, S, 6*D].
//
// Pure memory-bound gather. One block per (b,t,di) output row of D=1024 floats,
// 256 threads x float4 each -> fully coalesced 16B/lane loads and stores.

constexpr unsigned B = 4;
constexpr unsigned S = 4096;          // power of two
constexpr unsigned D = 1024;
constexpr unsigned ND = 6;            // number of delays; DELAYS[i] = 1u << i
constexpr unsigned D4 = D / 4;        // float4 per row = 256

__global__ __launch_bounds__(256) void delay_buffer_kernel(
    const float4* __restrict__ in, float4* __restrict__ out) {
    const unsigned bid = blockIdx.x;          // (b*S + t)*6 + di
    const unsigned di  = bid % ND;            // uniform magic-mul
    const unsigned bt  = bid / ND;            // b*S + t
    const unsigned t   = bt & (S - 1);
    const unsigned d   = 1u << di;            // delay value
    const unsigned src_bt = (t >= d) ? (bt - d) : bt;   // shift within same b (t>=d guarantees no row underflow)

    out[(size_t)bid * D4 + threadIdx.x] = in[(size_t)src_bt * D4 + threadIdx.x];
}

extern "C" void kernel_launch(void* const* d_in, const int* in_sizes, int n_in,
                              void* d_out, int out_size, void* d_ws, size_t ws_size,
                              hipStream_t stream) {
    const float4* in  = (const float4*)d_in[0];
    float4*       out = (float4*)d_out;

    const unsigned grid = B * S * ND;         // 98304 blocks
    delay_buffer_kernel<<<grid, 256, 0, stream>>>(in, out);
}

// Round 4
// 433.772 us; speedup vs baseline: 1.0780x; 1.0780x over previous
//
#include <hip/hip_runtime.h>

// DelayBuffer: embeddings [B=4, S=4096, D=1024] f32.
// out[b, t, di*D + c] = emb[b, t - d, c] if t >= d else emb[b, t, c],  d = 1<<di.
//
// SCATTER formulation: one block per INPUT row (b,t). Reads the row exactly
// once (67 MB compulsory read traffic, no reuse needed), then stores it to
// every output row that needs it:
//   - out[b, t+d, di]  for each di with t+d < S   (the shifted copy)
//   - out[b, t,   di]  for each di with t < d     (the boundary passthrough)
// Every output row receives exactly one write. All stores are contiguous
// 4 KB rows -> fully coalesced. Branch conditions depend only on
// block-uniform t -> no divergence. Touch-once traffic -> nontemporal.

using f32x4 = __attribute__((ext_vector_type(4))) float;  // native vector for nontemporal builtins

constexpr unsigned B  = 4;
constexpr unsigned S  = 4096;          // power of two
constexpr unsigned ND = 6;             // delays d = 1<<di, di in [0,6)
constexpr unsigned D4 = 1024 / 4;      // float4 per row = 256
constexpr unsigned NROWS = B * S;      // 16384 input rows

__global__ __launch_bounds__(256) void delay_scatter(
    const f32x4* __restrict__ in, f32x4* __restrict__ out) {
    const unsigned tid = threadIdx.x;
    for (unsigned row = blockIdx.x; row < NROWS; row += gridDim.x) {
        const unsigned t = row & (S - 1);
        const f32x4 v = __builtin_nontemporal_load(&in[(size_t)row * D4 + tid]);
        const size_t ob = (size_t)row * (ND * D4) + tid;   // out row (b,t), di=0
        #pragma unroll
        for (unsigned di = 0; di < ND; ++di) {
            const unsigned d = 1u << di;
            if (t + d < S)   // out[b, t+d, di] = emb[b, t]
                __builtin_nontemporal_store(v, &out[ob + (size_t)(d * ND + di) * D4]);
            if (t < d)       // out[b, t, di] = emb[b, t]  (boundary passthrough)
                __builtin_nontemporal_store(v, &out[ob + (size_t)di * D4]);
        }
    }
}

extern "C" void kernel_launch(void* const* d_in, const int* in_sizes, int n_in,
                              void* d_out, int out_size, void* d_ws, size_t ws_size,
                              hipStream_t stream) {
    const f32x4* in  = (const f32x4*)d_in[0];
    f32x4*       out = (f32x4*)d_out;

    // 2048 blocks (8 per CU), grid-stride over 16384 rows -> 8 rows/block,
    // giving each wave 8 independent load->6-store pipelines for latency hiding.
    delay_scatter<<<2048, 256, 0, stream>>>(in, out);
}